// Round 8
// baseline (95.328 us; speedup 1.0000x reference)
//
#include <hip/hip_runtime.h>

#define IYD 192
#define IZD 160
#define PLANE 30720        // IYD*IZD
#define VOLSZ 4915200      // 160*PLANE
#define YG 191
#define ZG 159

// LDS float layout (6040 floats = 24160 B):
// raw[2v][15 rows][44] @0, size 1320 (z rel 0..39 = global z0-4..z0+35)
// PB[par] @ 1320 + par*2360:
//   ZB [2v][15][36] @+0    : z-box of raw (col c: window rel [c+2,c+8])
//   YB [2v][8][44]  @+1080 : y-box of raw (rows oy+1..oy+7, masked)
//   TB [2v][8][36]  @+1784 : z-box of YB
#define RAWV 660
#define RAWR 44
#define PB0 1320
#define PBS 2360
#define ZBV 540
#define ZBR 36
#define YBO 1080
#define YBV 352
#define YBR 44
#define TBO 1784
#define TBV 288
#define TBR 36
#define LDSF 6040

#define NVOX_INV (1.0f / 9657342.0f)   // 2*159*191*159

__device__ __forceinline__ float4 f4add(float4 a, float4 b) {
    return make_float4(a.x + b.x, a.y + b.y, a.z + b.z, a.w + b.w);
}
__device__ __forceinline__ float4 f4sub(float4 a, float4 b) {
    return make_float4(a.x - b.x, a.y - b.y, a.z - b.z, a.w - b.w);
}
__device__ __forceinline__ float4 f4scale(float4 a, float s) {
    return make_float4(a.x * s, a.y * s, a.z * s, a.w * s);
}

__global__ __launch_bounds__(256, 4) void grad_sim_v8(
    const float* __restrict__ Ii, const float* __restrict__ Ji,
    float* __restrict__ out)
{
    __shared__ __align__(16) float lds[LDSF];
    const int tid = threadIdx.x;
    const int z0 = (int)blockIdx.x * 32;
    const int y0 = (int)blockIdx.y * 8;
    const int seg = blockIdx.z & 7;
    const int bat = blockIdx.z >> 3;
    const int s0 = seg * 20;
    const int a0 = (seg == 0) ? 0 : (s0 - 3);
    const int aLast = (seg == 7) ? 159 : (s0 + 23);

    const float* __restrict__ bI = Ii + (size_t)bat * VOLSZ;
    const float* __restrict__ bJ = Ji + (size_t)bat * VOLSZ;

    // ---- per-thread float4 halo-load tasks: 2v x 15 rows x 10 quads = 300 ----
    const float* gq0; const float* gq1;
    int lq0, lq1; float mq0, mq1;
    {
        int q = tid;
        int v = q / 150; int rr = q - v * 150;
        int row = rr / 10; int qd = rr - row * 10;
        int iy = y0 - 3 + row; int izb = z0 - 4 + 4 * qd;
        bool ok = ((unsigned)iy < IYD) && (izb >= 0) && (izb + 3 <= 159);
        int iyc = min(max(iy, 0), IYD - 1); int izc = min(max(izb, 0), 156);
        gq0 = (v ? bJ : bI) + (iyc * IZD + izc);
        lq0 = v * RAWV + row * RAWR + 4 * qd;
        mq0 = ok ? 1.f : 0.f;
    }
    {
        int q = 256 + tid;
        int v = q / 150; int rr = q - v * 150;
        int row = rr / 10; int qd = rr - row * 10;
        int iy = y0 - 3 + row; int izb = z0 - 4 + 4 * qd;
        bool ok = ((unsigned)iy < IYD) && (izb >= 0) && (izb + 3 <= 159);
        int iyc = min(max(iy, 0), IYD - 1); int izc = min(max(izb, 0), 156);
        gq1 = (v ? bJ : bI) + (iyc * IZD + izc);
        lq1 = v * RAWV + row * RAWR + 4 * qd;
        mq1 = ok ? 1.f : 0.f;
    }

    // ---- E1 decode (120 lanes): (vol, row 0..14, zq 0..3) -> ZB ----
    const int zv = tid / 60;
    const int zrr = tid - 60 * zv;
    const int zr = zrr >> 2;
    const int zq = zrr & 3;
    const bool doZ = tid < 120;
    const bool zlo1 = (z0 == 0) && (zq == 0);
    const int rawRd = zv * RAWV + zr * RAWR + 8 * zq;
    const int zbWr = zv * ZBV + zr * ZBR + 8 * zq;

    // ---- E2a decode (lanes 128..147): (v, zqd 0..9) -> YB ----
    const int t2a = tid - 128;
    const bool doYA = (t2a >= 0) && (t2a < 20);
    const int t2s = doYA ? t2a : 0;
    const int aZq = t2s % 10;
    const int aV = t2s / 10;
    const int aRawB = aV * RAWV + 4 * aZq;
    const int aYbB = YBO + aV * YBV + 4 * aZq;
    const float mlo = (y0 == 0) ? 0.f : 1.f;
    const float mhi = (y0 == 184) ? 0.f : 1.f;

    // ---- E2b decode (64 lanes): (v, oy, zq 0..3): YB -> TB ----
    const bool doTB = tid < 64;
    const int bV = tid >> 5;
    const int bR = tid & 31;
    const int bOy = bR >> 2;
    const int bZq = bR & 3;
    const bool zlo2 = (z0 == 0) && (bZq == 0);
    const int ybRd = YBO + bV * YBV + bOy * YBR + 8 * bZq;
    const int tbWr = TBO + bV * TBV + bOy * TBR + 8 * bZq;

    // ---- E3 per-thread column ----
    const int oy = tid >> 5;
    const int oz = tid & 31;
    const int ygl = y0 + oy;
    const int vmax = min(3, 190 - ygl);
    const int vmin = max(-3, -ygl);
    const int oT = TBO + oy * TBR + oz;
    const int oVhi = (oy + vmax + 4) * ZBR + oz;
    const int oVlo = (oy + vmin + 3) * ZBR + oz;
    const int relHiZ = min(oz + 8, (z0 == 128) ? 35 : 63);
    const int relLoZ = max(oz + 1, (z0 == 0) ? 4 : 0);
    const int oWhi = YBO + oy * YBR + relHiZ;
    const int oWlo = YBO + oy * YBR + relLoZ;
    const bool okyz = (ygl < YG) && ((z0 + oz) < ZG);

    // x rings (static indices only)
    float Tr[2][8], Vr[2][8], Wr[2][8], Sdy[2], Sdz[2];
#pragma unroll
    for (int v = 0; v < 2; ++v) {
#pragma unroll
        for (int j = 0; j < 8; ++j) { Tr[v][j] = 0.f; Vr[v][j] = 0.f; Wr[v][j] = 0.f; }
        Sdy[v] = 0.f; Sdz[v] = 0.f;
    }
    float acc = 0.f;

    // ---- prologue: land raw plane a0 ----
    {
        const size_t pb = (size_t)a0 * PLANE;
        float4 t0 = f4scale(*(const float4*)(gq0 + pb), mq0);
        *(float4*)&lds[lq0] = t0;
        if (tid < 44) {
            float4 t1 = f4scale(*(const float4*)(gq1 + pb), mq1);
            *(float4*)&lds[lq1] = t1;
        }
    }
    __syncthreads();

    for (int ag = (a0 & ~7); ag <= aLast + 1; ag += 8) {
#pragma unroll
        for (int u = 0; u < 8; ++u) {
            const int t = ag + u;
            if (t < a0 || t > aLast + 1) continue;   // uniform
            const int PBp = PB0 + (u & 1) * PBS;
            const int PBq = PB0 + ((u + 1) & 1) * PBS;

            // issue prefetch of plane t+1
            const bool dof = (t + 1) <= aLast;
            float4 pf0, pf1;
            if (dof) {
                const size_t pb = (size_t)(t + 1) * PLANE;
                pf0 = *(const float4*)(gq0 + pb);
                if (tid < 44) pf1 = *(const float4*)(gq1 + pb);
            }

            // ---- E1: z-box of raw plane t -> ZB[p] ----
            if (t <= aLast && doZ) {
                float C[16];
                const float4* rb = (const float4*)&lds[rawRd];
#pragma unroll
                for (int q = 0; q < 4; ++q) ((float4*)C)[q] = rb[q];
                if (zlo1) { C[2] = 0.f; C[3] = 0.f; C[4] = 0.f; }
                float Z[8];
                float w = C[2] + C[3] + C[4] + C[5] + C[6] + C[7] + C[8];
                Z[0] = w;
#pragma unroll
                for (int m = 1; m < 8; ++m) { w += C[m + 8] - C[m + 1]; Z[m] = w; }
                float4* zb = (float4*)&lds[PBp + zbWr];
                zb[0] = make_float4(Z[0], Z[1], Z[2], Z[3]);
                zb[1] = make_float4(Z[4], Z[5], Z[6], Z[7]);
            }

            // ---- E2a: y-box of raw plane t -> YB[p] (rolling slide) ----
            if (t <= aLast && doYA) {
                const float* rb = &lds[aRawB];
                float4 r1 = f4scale(*(const float4*)&rb[1 * RAWR], mlo);
                float4 r2 = f4scale(*(const float4*)&rb[2 * RAWR], mlo);
                float4 r3 = f4scale(*(const float4*)&rb[3 * RAWR], mlo);
                float4 r4 = *(const float4*)&rb[4 * RAWR];
                float4 r5 = *(const float4*)&rb[5 * RAWR];
                float4 r6 = *(const float4*)&rb[6 * RAWR];
                float4 r7 = *(const float4*)&rb[7 * RAWR];
                float4 w = f4add(f4add(f4add(r1, r2), f4add(r3, r4)),
                                 f4add(f4add(r5, r6), r7));
                *(float4*)&lds[PBp + aYbB] = w;
                float4 rn;
                rn = *(const float4*)&rb[8 * RAWR];
                w = f4add(w, f4sub(rn, r1));
                *(float4*)&lds[PBp + aYbB + 1 * YBR] = w;
                rn = *(const float4*)&rb[9 * RAWR];
                w = f4add(w, f4sub(rn, r2));
                *(float4*)&lds[PBp + aYbB + 2 * YBR] = w;
                rn = *(const float4*)&rb[10 * RAWR];
                w = f4add(w, f4sub(rn, r3));
                *(float4*)&lds[PBp + aYbB + 3 * YBR] = w;
                rn = f4scale(*(const float4*)&rb[11 * RAWR], mhi);
                w = f4add(w, f4sub(rn, r4));
                *(float4*)&lds[PBp + aYbB + 4 * YBR] = w;
                rn = f4scale(*(const float4*)&rb[12 * RAWR], mhi);
                w = f4add(w, f4sub(rn, r5));
                *(float4*)&lds[PBp + aYbB + 5 * YBR] = w;
                rn = f4scale(*(const float4*)&rb[13 * RAWR], mhi);
                w = f4add(w, f4sub(rn, r6));
                *(float4*)&lds[PBp + aYbB + 6 * YBR] = w;
                rn = f4scale(*(const float4*)&rb[14 * RAWR], mhi);
                w = f4add(w, f4sub(rn, r7));
                *(float4*)&lds[PBp + aYbB + 7 * YBR] = w;
            }

            // ---- E3: ring push for plane aa = t-1 (reads PB[q]) ----
            if (t - 1 >= a0) {
                const int aa = t - 1;
                float tI = lds[PBq + oT];
                float tJ = lds[PBq + oT + TBV];
                float vI = lds[PBq + oVhi] - lds[PBq + oVlo];
                float vJ = lds[PBq + oVhi + ZBV] - lds[PBq + oVlo + ZBV];
                float wI = lds[PBq + oWhi] - lds[PBq + oWlo];
                float wJ = lds[PBq + oWhi + YBV] - lds[PBq + oWlo + YBV];
                if (aa == a0) { vI = 0.f; vJ = 0.f; wI = 0.f; wJ = 0.f; }
                const int p = (u + 7) & 7;       // = aa & 7, compile-time
                const int p1 = (p + 1) & 7;
                float hdxI = tI - Tr[0][p1];
                float hdxJ = tJ - Tr[1][p1];
                Sdy[0] += vI - Vr[0][p1]; Vr[0][p] = vI;
                Sdy[1] += vJ - Vr[1][p1]; Vr[1][p] = vJ;
                Sdz[0] += wI - Wr[0][p1]; Wr[0][p] = wI;
                Sdz[1] += wJ - Wr[1][p1]; Wr[1][p] = wJ;
                Tr[0][p] = tI; Tr[1][p] = tJ;
                if (p == 0 && aa == 0) {   // seed clamped prefix T[0] for x=0,1,2
                    Tr[0][5] = tI; Tr[0][6] = tI; Tr[0][7] = tI;
                    Tr[1][5] = tJ; Tr[1][6] = tJ; Tr[1][7] = tJ;
                }
                if (aa >= s0 + 4) {
                    float cross = fabsf(hdxI * hdxJ + Sdy[0] * Sdy[1] + Sdz[0] * Sdz[1]) + 0.01f;
                    float dI = hdxI * hdxI + Sdy[0] * Sdy[0] + Sdz[0] * Sdz[0] + 0.01f;
                    float dJ = hdxJ * hdxJ + Sdy[1] * Sdy[1] + Sdz[1] * Sdz[1] + 0.01f;
                    float val = cross * rsqrtf(dI * dJ);
                    if (okyz) acc += val;
                }
            }
            __syncthreads();

            // ---- epoch 2: E2b (T = zbox(YB[p])) + land raw(t+1) ----
            if (t <= aLast && doTB) {
                float C[16];
                const float4* yb = (const float4*)&lds[PBp + ybRd];
#pragma unroll
                for (int q = 0; q < 4; ++q) ((float4*)C)[q] = yb[q];
                if (zlo2) { C[2] = 0.f; C[3] = 0.f; C[4] = 0.f; }
                float Z[8];
                float w = C[2] + C[3] + C[4] + C[5] + C[6] + C[7] + C[8];
                Z[0] = w;
#pragma unroll
                for (int m = 1; m < 8; ++m) { w += C[m + 8] - C[m + 1]; Z[m] = w; }
                float4* tb = (float4*)&lds[PBp + tbWr];
                tb[0] = make_float4(Z[0], Z[1], Z[2], Z[3]);
                tb[1] = make_float4(Z[4], Z[5], Z[6], Z[7]);
            }
            if (dof) {
                *(float4*)&lds[lq0] = f4scale(pf0, mq0);
                if (tid < 44) *(float4*)&lds[lq1] = f4scale(pf1, mq1);
            }
            __syncthreads();
        }
    }

    // ---- register-only tail (seg 7): x = 156,157,158 ----
    if (seg == 7) {
#pragma unroll
        for (int tt = 0; tt < 3; ++tt) {
            const int sl = tt + 1;               // planes 153,154,155
            float hdxI = Tr[0][7] - Tr[0][sl];   // T[159] - T[x-3]
            float hdxJ = Tr[1][7] - Tr[1][sl];
            Sdy[0] -= Vr[0][sl]; Sdy[1] -= Vr[1][sl];
            Sdz[0] -= Wr[0][sl]; Sdz[1] -= Wr[1][sl];
            float cross = fabsf(hdxI * hdxJ + Sdy[0] * Sdy[1] + Sdz[0] * Sdz[1]) + 0.01f;
            float dI = hdxI * hdxI + Sdy[0] * Sdy[0] + Sdz[0] * Sdz[0] + 0.01f;
            float dJ = hdxJ * hdxJ + Sdy[1] * Sdy[1] + Sdz[1] * Sdz[1] + 0.01f;
            float val = cross * rsqrtf(dI * dJ);
            if (okyz) acc += val;
        }
    }

    // ---- block reduce + atomic ----
#pragma unroll
    for (int off = 32; off > 0; off >>= 1) acc += __shfl_down(acc, off, 64);
    __syncthreads();
    if ((tid & 63) == 0) lds[tid >> 6] = acc;
    __syncthreads();
    if (tid == 0)
        atomicAdd(out, (lds[0] + lds[1] + lds[2] + lds[3]) * NVOX_INV);
}

extern "C" void kernel_launch(void* const* d_in, const int* in_sizes, int n_in,
                              void* d_out, int out_size, void* d_ws, size_t ws_size,
                              hipStream_t stream) {
    const float* Ii = (const float*)d_in[0];
    const float* Ji = (const float*)d_in[1];
    float* out = (float*)d_out;
    hipMemsetAsync(d_out, 0, sizeof(float) * (out_size > 0 ? out_size : 1), stream);
    dim3 grid(5, 24, 16);   // z-tiles(32) x y-tiles(8) x (8 x-segments * 2 batches)
    grad_sim_v8<<<grid, dim3(256), 0, stream>>>(Ii, Ji, out);
}